// Round 1
// baseline (465.345 us; speedup 1.0000x reference)
//
#include <hip/hip_runtime.h>
#include <hip/hip_bf16.h>
#include <math.h>

typedef __bf16 bf16_t;
typedef __bf16 bf16x8 __attribute__((ext_vector_type(8)));
typedef float f32x4 __attribute__((ext_vector_type(4)));

#define AS1q __attribute__((address_space(1)))
#define AS3q __attribute__((address_space(3)))

// async global->LDS, 16B per lane; LDS dest = wave-uniform base + lane*16
__device__ __forceinline__ void gload_lds16(const bf16_t* g, bf16_t* l) {
    __builtin_amdgcn_global_load_lds((AS1q void*)g, (AS3q void*)l, 16, 0, 0);
}

// ------------------------------------------------------------------
// constants for this problem (B=1, H=W=T=48, C=96, nh=3, hd=32)
// ------------------------------------------------------------------
#define LROWS   110592        // H*W*T
#define CDIM    96
#define NTOK    2304          // H*W
#define FDIM    1536          // B_*hd
#define YSTR    3538944ll     // 2304*1536 (per-g stride in Y)
#define SSTR    5308416ll     // 2304*2304
#define SCALE_Q 0.1767766952966369f   // 32^-0.5

// ------------------------------------------------------------------
// weight fp32 -> bf16 (qkv 27648 | proj 9216 | fc1 36864 | fc2 36864)
// ------------------------------------------------------------------
__global__ __launch_bounds__(256)
void conv_w(const float* __restrict__ a, const float* __restrict__ b,
            const float* __restrict__ c, const float* __restrict__ d,
            bf16_t* __restrict__ out)
{
    int i = blockIdx.x * 256 + threadIdx.x;   // 110592 total
    float v;
    if (i < 27648)       v = a[i];
    else if (i < 36864)  v = b[i - 27648];
    else if (i < 73728)  v = c[i - 36864];
    else                 v = d[i - 73728];
    out[i] = (bf16_t)v;
}

// ------------------------------------------------------------------
// LayerNorm over C=96, one wave per row; optional axial permute on output:
// src row l = n*48 + t  ->  dst row t*2304 + n
// ------------------------------------------------------------------
__global__ __launch_bounds__(256)
void ln_kernel(const float* __restrict__ x, const float* __restrict__ gamma,
               const float* __restrict__ beta, bf16_t* __restrict__ out, int permute)
{
    int wave = threadIdx.x >> 6, lane = threadIdx.x & 63;
    int row = blockIdx.x * 4 + wave;
    const float* xr = x + (size_t)row * CDIM;
    float e0 = xr[lane];
    float e1 = (lane < 32) ? xr[64 + lane] : 0.f;
    float s = e0 + e1;
    for (int off = 32; off > 0; off >>= 1) s += __shfl_xor(s, off, 64);
    float mean = s * (1.f / 96.f);
    float d0 = e0 - mean;
    float d1 = (lane < 32) ? (e1 - mean) : 0.f;
    float vs = d0 * d0 + d1 * d1;
    for (int off = 32; off > 0; off >>= 1) vs += __shfl_xor(vs, off, 64);
    float rstd = rsqrtf(vs * (1.f / 96.f) + 1e-5f);
    size_t orow = row;
    if (permute) { int t = row % 48; int n = row / 48; orow = (size_t)t * NTOK + n; }
    bf16_t* o = out + orow * CDIM;
    o[lane] = (bf16_t)(d0 * rstd * gamma[lane] + beta[lane]);
    if (lane < 32) o[64 + lane] = (bf16_t)(d1 * rstd * gamma[64 + lane] + beta[64 + lane]);
}

// ------------------------------------------------------------------
// V transpose: Y[6+z][n][m] -> Yv[z][m][n]   (64x64 LDS tiles)
// ------------------------------------------------------------------
__global__ __launch_bounds__(256)
void transpose_v(const bf16_t* __restrict__ Y, bf16_t* __restrict__ Yv)
{
    __shared__ bf16_t tile[64][65];
    const bf16_t* src = Y + (size_t)(6 + blockIdx.z) * YSTR;
    bf16_t* dst = Yv + (size_t)blockIdx.z * YSTR;
    int m0 = blockIdx.x * 64, n0 = blockIdx.y * 64;
    int nl = threadIdx.x >> 2, ch = threadIdx.x & 3;
    const bf16x8* s8 = (const bf16x8*)(src + (size_t)(n0 + nl) * FDIM + m0 + ch * 16);
    bf16x8 va = s8[0], vb = s8[1];
    #pragma unroll
    for (int j = 0; j < 8; j++) tile[nl][ch * 16 + j] = va[j];
    #pragma unroll
    for (int j = 0; j < 8; j++) tile[nl][ch * 16 + 8 + j] = vb[j];
    __syncthreads();
    bf16_t* d = dst + (size_t)(m0 + nl) * NTOK + n0 + ch * 16;
    #pragma unroll
    for (int j = 0; j < 16; j++) d[j] = tile[ch * 16 + j][nl];
}

// ------------------------------------------------------------------
// row softmax over 2304: S (f32) -> P (bf16).  One block (256 thr) per row.
// ------------------------------------------------------------------
__global__ __launch_bounds__(256)
void softmax_k(const float* __restrict__ S, bf16_t* __restrict__ P,
               long long sZ, long long pZ)
{
    __shared__ float red[8];
    const float* sr = S + (size_t)blockIdx.z * sZ + (size_t)blockIdx.x * NTOK;
    bf16_t* pr = P + (size_t)blockIdx.z * pZ + (size_t)blockIdx.x * NTOK;
    int wave = threadIdx.x >> 6, lane = threadIdx.x & 63;
    float v[9];
    float mx = -1e30f;
    #pragma unroll
    for (int t = 0; t < 9; t++) { v[t] = sr[t * 256 + threadIdx.x]; mx = fmaxf(mx, v[t]); }
    for (int off = 32; off > 0; off >>= 1) mx = fmaxf(mx, __shfl_xor(mx, off, 64));
    if (lane == 0) red[wave] = mx;
    __syncthreads();
    mx = fmaxf(fmaxf(red[0], red[1]), fmaxf(red[2], red[3]));
    float sum = 0.f;
    #pragma unroll
    for (int t = 0; t < 9; t++) { v[t] = __expf(v[t] - mx); sum += v[t]; }
    for (int off = 32; off > 0; off >>= 1) sum += __shfl_xor(sum, off, 64);
    if (lane == 0) red[4 + wave] = sum;
    __syncthreads();
    sum = red[4] + red[5] + red[6] + red[7];
    float inv = 1.f / sum;
    #pragma unroll
    for (int t = 0; t < 9; t++) pr[t * 256 + threadIdx.x] = (bf16_t)(v[t] * inv);
}

// ------------------------------------------------------------------
// bf16 MFMA GEMM:  C[M,N] = A[M,K] @ W[N,K]^T  (+ fused epilogue)
// BM=128, BK=32, 256 threads (2x2 waves, each 64 x BN/2).
// EPI: 0=QKV scatter(+bias)  1=S f32 (*scale)  2=PV scatter (o_rows)
//      3=bias+GELU bf16      4=bias+residual f32
// ------------------------------------------------------------------
template<int BN, int EPI>
__global__ __launch_bounds__(256, 2)
void gemm_bt(const bf16_t* __restrict__ A, const bf16_t* __restrict__ W,
             void* __restrict__ out, const float* __restrict__ bias,
             const float* __restrict__ resid, int K, int ldo,
             long long aZ, long long wZ, long long oZ, float scale, int head0)
{
    constexpr int BM = 128, BK = 32;
    constexpr int NT = BN / 32;              // n-tiles per wave
    __shared__ bf16_t As[BM * BK];
    __shared__ bf16_t Bs[BN * BK];

    const int tid = threadIdx.x;
    const int wave = tid >> 6, lane = tid & 63;
    const int quad = lane >> 4, l16 = lane & 15;
    const int wm = wave & 1, wn = wave >> 1;
    const int z = blockIdx.z;
    A += (size_t)z * aZ;
    W += (size_t)z * wZ;
    const int m0 = blockIdx.x * BM, n0 = blockIdx.y * BN;

    f32x4 acc[4][NT];
    #pragma unroll
    for (int i = 0; i < 4; i++)
        #pragma unroll
        for (int j = 0; j < NT; j++) { f32x4 zz = {0.f, 0.f, 0.f, 0.f}; acc[i][j] = zz; }

    const int srow = lane >> 2;   // row within a 16-row issue
    const int scol = lane & 3;    // 16B chunk slot

    for (int k0 = 0; k0 < K; k0 += BK) {
        __syncthreads();   // prior compute done reading LDS
        // A tile: 128 rows x 64B; issue = 16 rows (1024B)
        for (int it = wave; it < BM / 16; it += 4) {
            int r = it * 16 + srow;
            int cg = scol ^ (r & 3);                     // XOR swizzle
            gload_lds16(A + (size_t)(m0 + r) * K + k0 + cg * 8, &As[it * 512]);
        }
        for (int it = wave; it < BN / 16; it += 4) {
            int r = it * 16 + srow;
            int cg = scol ^ (r & 3);
            gload_lds16(W + (size_t)(n0 + r) * K + k0 + cg * 8, &Bs[it * 512]);
        }
        __syncthreads();   // barrier emits vmcnt(0) drain -> LDS valid

        bf16x8 af[4], bfr[NT];
        #pragma unroll
        for (int i = 0; i < 4; i++) {
            int r = wm * 64 + i * 16 + l16;
            af[i] = *(const bf16x8*)&As[r * 32 + ((quad ^ (r & 3)) << 3)];
        }
        #pragma unroll
        for (int j = 0; j < NT; j++) {
            int c = wn * (BN / 2) + j * 16 + l16;
            bfr[j] = *(const bf16x8*)&Bs[c * 32 + ((quad ^ (c & 3)) << 3)];
        }
        #pragma unroll
        for (int i = 0; i < 4; i++)
            #pragma unroll
            for (int j = 0; j < NT; j++)
                acc[i][j] = __builtin_amdgcn_mfma_f32_16x16x32_bf16(af[i], bfr[j], acc[i][j], 0, 0, 0);
    }

    // epilogue: D[row=quad*4+ri][col=l16] per 16x16 tile
    if constexpr (EPI == 0) {
        // QKV scatter: block rows all share t (2304 % 128 == 0)
        const int t = m0 / NTOK;
        const int nb = m0 - t * NTOK;
        #pragma unroll
        for (int j = 0; j < NT; j++) {
            int c = n0 + wn * (BN / 2) + j * 16 + l16;
            int jj = t * 288 + c;
            int g = jj / FDIM;
            int mm = jj - g * FDIM;
            float bv = bias[c];
            bf16_t* yp = (bf16_t*)out + (size_t)g * YSTR + mm;
            #pragma unroll
            for (int i = 0; i < 4; i++)
                #pragma unroll
                for (int ri = 0; ri < 4; ri++) {
                    int n = nb + wm * 64 + i * 16 + quad * 4 + ri;
                    yp[(size_t)n * FDIM] = (bf16_t)(acc[i][j][ri] + bv);
                }
        }
    } else {
        #pragma unroll
        for (int i = 0; i < 4; i++)
            #pragma unroll
            for (int j = 0; j < NT; j++)
                #pragma unroll
                for (int ri = 0; ri < 4; ri++) {
                    int r = m0 + wm * 64 + i * 16 + quad * 4 + ri;
                    int c = n0 + wn * (BN / 2) + j * 16 + l16;
                    float v = acc[i][j][ri];
                    if constexpr (EPI == 1) {
                        float* op = (float*)out + (size_t)z * oZ;
                        op[(size_t)r * NTOK + c] = v * scale;
                    } else if constexpr (EPI == 2) {
                        int h = head0 + z;
                        int b = r / 48, rr = r - b * 48;
                        ((bf16_t*)out)[((size_t)(b * NTOK + rr * 48 + h * 16)) * CDIM + c] = (bf16_t)v;
                    } else if constexpr (EPI == 3) {
                        float u = v + bias[c];
                        u = 0.5f * u * (1.0f + erff(u * 0.70710678118654752f));
                        ((bf16_t*)out)[(size_t)r * ldo + c] = (bf16_t)u;
                    } else {
                        float u = v + bias[c] + resid[(size_t)r * ldo + c];
                        ((float*)out)[(size_t)r * ldo + c] = u;
                    }
                }
    }
}

// ------------------------------------------------------------------
extern "C" void kernel_launch(void* const* d_in, const int* in_sizes, int n_in,
                              void* d_out, int out_size, void* d_ws, size_t ws_size,
                              hipStream_t stream)
{
    const float* x      = (const float*)d_in[0];
    const float* ln1_g  = (const float*)d_in[2];
    const float* ln1_b  = (const float*)d_in[3];
    const float* qkv_w  = (const float*)d_in[4];
    const float* qkv_b  = (const float*)d_in[5];
    const float* proj_w = (const float*)d_in[6];
    const float* proj_b = (const float*)d_in[7];
    const float* ln2_g  = (const float*)d_in[8];
    const float* ln2_b  = (const float*)d_in[9];
    const float* fc1_w  = (const float*)d_in[10];
    const float* fc1_b  = (const float*)d_in[11];
    const float* fc2_w  = (const float*)d_in[12];
    const float* fc2_b  = (const float*)d_in[13];

    // ---- workspace layout (all sizes 256B-multiples) ----
    const size_t SZ_WB = 110592ull * 2;          // bf16 weights
    const size_t SZ_HP = 10616832ull * 2;        // hp / o_rows / h2
    const size_t SZ_Y  = 31850496ull * 2;        // Y [9][2304][1536]
    const size_t SZ_YV = 10616832ull * 2;        // Yv [3][1536][2304]
    const size_t SZ_S1 = 5308416ull * 4;         // S per head (f32)
    const size_t SZ_P1 = 5308416ull * 2;         // P per head (bf16)
    const size_t SZ_X2 = 10616832ull * 4;        // x2 (f32)

    char* ws = (char*)d_ws;
    size_t oWB = 0;
    size_t oHP = oWB + SZ_WB;
    size_t oY  = oHP + SZ_HP;
    size_t oYV = oY + SZ_Y;
    size_t oS  = oYV + SZ_YV;
    size_t needBig   = oS + 3 * SZ_S1 + 3 * SZ_P1 + SZ_X2;
    bool big = (ws_size >= needBig);
    size_t oP  = oS + (big ? 3 * SZ_S1 : SZ_S1);
    size_t oX2 = oP + (big ? 3 * SZ_P1 : SZ_P1);

    bf16_t* Wb    = (bf16_t*)(ws + oWB);
    bf16_t* Wqkv  = Wb;
    bf16_t* Wproj = Wb + 27648;
    bf16_t* Wfc1  = Wb + 36864;
    bf16_t* Wfc2  = Wb + 73728;
    bf16_t* hp    = (bf16_t*)(ws + oHP);   // then o_rows, then h2
    bf16_t* Y     = (bf16_t*)(ws + oY);
    bf16_t* Yv    = (bf16_t*)(ws + oYV);
    bf16_t* t1    = (bf16_t*)(ws + oY);    // reuses Y+Yv (exact fit)
    float*  Sb    = (float*)(ws + oS);
    bf16_t* Pb    = (bf16_t*)(ws + oP);
    float*  x2    = (float*)(ws + oX2);
    float*  outp  = (float*)d_out;

    dim3 blk(256);

    // 1. weights -> bf16
    conv_w<<<dim3(432), blk, 0, stream>>>(qkv_w, proj_w, fc1_w, fc2_w, Wb);
    // 2. LN1 + axial permute -> hp [48][2304][96]
    ln_kernel<<<dim3(27648), blk, 0, stream>>>(x, ln1_g, ln1_b, hp, 1);
    // 3. QKV gemm -> Y (scattered to [g][n][m])
    gemm_bt<96, 0><<<dim3(864, 3), blk, 0, stream>>>(hp, Wqkv, Y, qkv_b, nullptr,
                                                     96, 0, 0, 0, 0, 0.f, 0);
    // 4. V transpose -> Yv [h][m][n]
    transpose_v<<<dim3(24, 36, 3), blk, 0, stream>>>(Y, Yv);

    // 5-7. attention
    if (big) {
        gemm_bt<128, 1><<<dim3(18, 18, 3), blk, 0, stream>>>(Y, Y + 3 * YSTR, Sb, nullptr, nullptr,
                                                             1536, 0, YSTR, YSTR, SSTR, SCALE_Q, 0);
        softmax_k<<<dim3(2304, 1, 3), blk, 0, stream>>>(Sb, Pb, SSTR, SSTR);
        gemm_bt<128, 2><<<dim3(18, 12, 3), blk, 0, stream>>>(Pb, Yv, hp, nullptr, nullptr,
                                                             2304, 0, SSTR, YSTR, 0, 0.f, 0);
    } else {
        for (int h = 0; h < 3; h++) {
            gemm_bt<128, 1><<<dim3(18, 18, 1), blk, 0, stream>>>(Y + (size_t)h * YSTR, Y + (size_t)(3 + h) * YSTR,
                                                                 Sb, nullptr, nullptr,
                                                                 1536, 0, 0, 0, 0, SCALE_Q, 0);
            softmax_k<<<dim3(2304, 1, 1), blk, 0, stream>>>(Sb, Pb, 0, 0);
            gemm_bt<128, 2><<<dim3(18, 12, 1), blk, 0, stream>>>(Pb, Yv + (size_t)h * YSTR, hp, nullptr, nullptr,
                                                                 2304, 0, 0, 0, 0, 0.f, h);
        }
    }

    // 8. proj + residual -> x2 (f32)   (o_rows lives in hp region)
    gemm_bt<96, 4><<<dim3(864, 1), blk, 0, stream>>>(hp, Wproj, x2, proj_b, x,
                                                     96, 96, 0, 0, 0, 0.f, 0);
    // 9. LN2 -> h2 (reuses hp region)
    ln_kernel<<<dim3(27648), blk, 0, stream>>>(x2, ln2_g, ln2_b, hp, 0);
    // 10. fc1 + GELU -> t1 (reuses Y+Yv region)
    gemm_bt<128, 3><<<dim3(864, 3), blk, 0, stream>>>(hp, Wfc1, t1, fc1_b, nullptr,
                                                      96, 384, 0, 0, 0, 0.f, 0);
    // 11. fc2 + residual -> out (f32)
    gemm_bt<96, 4><<<dim3(864, 1), blk, 0, stream>>>(t1, Wfc2, outp, fc2_b, x2,
                                                     384, 96, 0, 0, 0, 0.f, 0);
}